// Round 6
// baseline (156.670 us; speedup 1.0000x reference)
//
#include <hip/hip_runtime.h>
#include <hip/hip_bf16.h>

// out[b,t] = cumsum_t( relu(x @ Wh^T + bh) ) + (x @ Wb + bb)
// B=16384, D=1024, T=512. fp32 in/out; GEMM in bf16 MFMA (fp32 accum).
// R5: INVERT THE STAGING. B (Wh, 1MB) is L2-resident and has zero inter-wave
//     reuse within a block -> load B straight to VGPRs from global.
//     A (x tile) lives in LDS, staged in 4 K-chunks of 256 (double-buffered,
//     T14 split: issue x-loads early, convert+ds_write after compute).
//     Only 4 __syncthreads in the whole kernel; no per-K-step barriers.

typedef __bf16 bf16x8 __attribute__((ext_vector_type(8)));
typedef __bf16 bf16x4 __attribute__((ext_vector_type(4)));
typedef float f32x4 __attribute__((ext_vector_type(4)));

#define BM 64
#define KC 256          // K-chunk elements
#define NCH 4           // 1024/256
#define TDIM 512
#define DDIM 1024
#define AROWB 512       // bytes per A-LDS row (256 bf16)
#define ACHSZ (BM * AROWB)   // 32 KB per buffer

// ---- kernel 1: Wh fp32 -> bf16 ----
__global__ __launch_bounds__(256) void cvt_wh_kernel(const float* __restrict__ src,
                                                     __bf16* __restrict__ dst) {
    const int i = (blockIdx.x * 256 + threadIdx.x) * 4;
    const float4 v = *reinterpret_cast<const float4*>(src + i);
    bf16x4 o;
    o[0] = (__bf16)v.x; o[1] = (__bf16)v.y; o[2] = (__bf16)v.z; o[3] = (__bf16)v.w;
    *reinterpret_cast<bf16x4*>(dst + i) = o;
}

// swizzle the 16B slot within a 512B row by row&7: 16-row col-read becomes 2-way (free)
__device__ __forceinline__ int aswz(int row, int slotByte) {
    return (slotByte ^ ((row & 7) << 4));
}

// ---- kernel 2: fused GEMM + bias + relu + row-cumsum + base ----
__global__ __launch_bounds__(512, 2) void survival_kernel(
    const float* __restrict__ x,      // [16384][1024] fp32
    const __bf16* __restrict__ Whb,   // [512][1024] bf16
    const float* __restrict__ bh,     // [512]
    const float* __restrict__ Wb,     // [1024]
    const float* __restrict__ bbp,    // [1]
    float* __restrict__ out)          // [16384][512] fp32
{
    __shared__ __align__(16) char Alds[2][ACHSZ];   // 64 KB
    __shared__ float baseLds[BM];
    __shared__ float totLds[BM][8];

    const int tid  = threadIdx.x;
    const int lane = tid & 63;
    const int wid  = tid >> 6;     // 0..7 : wave owns cols wid*64..+63, ALL 64 rows
    const int brow = blockIdx.x * BM;
    const float bb0 = bbp[0];

    // --- A staging map: row = tid>>3, 32-elem segment = tid&7 ---
    const int ar = tid >> 3;       // 0..63
    const int ac = tid & 7;        // segment of 32 fp32
    const float* xrow = x + (size_t)(brow + ar) * DDIM + ac * 32;
    const float* wbp  = Wb + ac * 32;

    // --- B map: lane -> (t-col, k-quarter); 4 row-bases per wave ---
    const int tcol = lane & 15;
    const int kq   = lane >> 4;    // 0..3
    const __bf16* bbase[4];
#pragma unroll
    for (int n = 0; n < 4; ++n)
        bbase[n] = Whb + (size_t)(wid * 64 + n * 16 + tcol) * DDIM + kq * 8;

    float bpart = 0.f;
    f32x4 acc[4][4];
#pragma unroll
    for (int rt = 0; rt < 4; ++rt)
#pragma unroll
        for (int n = 0; n < 4; ++n)
            acc[rt][n] = (f32x4){0.f, 0.f, 0.f, 0.f};

    float4 xs[8];   // in-flight x chunk (static indexing under full unroll)

    auto issueX = [&](int c) {
#pragma unroll
        for (int j = 0; j < 8; ++j)
            xs[j] = *reinterpret_cast<const float4*>(xrow + c * KC + j * 4);
    };

    auto writeA = [&](int c, int buf) {
        // fused base-dot (Wb is L1/L2-resident, 4 KB)
#pragma unroll
        for (int j = 0; j < 8; ++j) {
            const float4 wv = *reinterpret_cast<const float4*>(wbp + c * KC + j * 4);
            bpart += xs[j].x * wv.x + xs[j].y * wv.y + xs[j].z * wv.z + xs[j].w * wv.w;
        }
        // convert + swizzled ds_write_b128 (4 slots of 8 bf16)
#pragma unroll
        for (int j2 = 0; j2 < 4; ++j2) {
            bf16x8 av;
            av[0] = (__bf16)xs[2*j2].x;   av[1] = (__bf16)xs[2*j2].y;
            av[2] = (__bf16)xs[2*j2].z;   av[3] = (__bf16)xs[2*j2].w;
            av[4] = (__bf16)xs[2*j2+1].x; av[5] = (__bf16)xs[2*j2+1].y;
            av[6] = (__bf16)xs[2*j2+1].z; av[7] = (__bf16)xs[2*j2+1].w;
            *reinterpret_cast<bf16x8*>(
                &Alds[buf][0] + ar * AROWB + aswz(ar, (ac * 4 + j2) * 16)) = av;
        }
    };

    auto computeC = [&](int c, int buf) {
        const char* Ab = &Alds[buf][0];
#pragma unroll
        for (int kst = 0; kst < 8; ++kst) {
            bf16x8 af[4];
#pragma unroll
            for (int rt = 0; rt < 4; ++rt) {
                const int row = rt * 16 + tcol;
                af[rt] = *reinterpret_cast<const bf16x8*>(
                    Ab + row * AROWB + aswz(row, kst * 64 + kq * 16));
            }
#pragma unroll
            for (int n = 0; n < 4; ++n) {
                const bf16x8 bfr = *reinterpret_cast<const bf16x8*>(
                    bbase[n] + c * KC + kst * 32);
#pragma unroll
                for (int rt = 0; rt < 4; ++rt)
                    acc[rt][n] = __builtin_amdgcn_mfma_f32_16x16x32_bf16(
                        af[rt], bfr, acc[rt][n], 0, 0, 0);
            }
        }
    };

    // --- chunked main loop: 4 chunks, T14 issue-early/write-late, dbuf LDS ---
    issueX(0);
    writeA(0, 0);
    __syncthreads();
#pragma unroll
    for (int c = 0; c < NCH; ++c) {
        if (c + 1 < NCH) issueX(c + 1);       // HBM latency hides under compute
        computeC(c, c & 1);
        if (c + 1 < NCH) writeA(c + 1, (c + 1) & 1);
        __syncthreads();
    }

    // --- base = x@Wb + bb : reduce 8 segment-partials per row ---
    bpart += __shfl_xor(bpart, 1, 8);
    bpart += __shfl_xor(bpart, 2, 8);
    bpart += __shfl_xor(bpart, 4, 8);
    if (ac == 0) baseLds[ar] = bpart + bb0;

    // --- epilogue: bias + relu + in-register inclusive scan over T ---
    // C layout (m89): col = lane&15, row = (lane>>4)*4 + j within 16x16 tile
    float bhv[4];
#pragma unroll
    for (int n = 0; n < 4; ++n)
        bhv[n] = bh[wid * 64 + n * 16 + tcol];

    float carry[4][4];
#pragma unroll
    for (int rt = 0; rt < 4; ++rt)
#pragma unroll
        for (int j = 0; j < 4; ++j) carry[rt][j] = 0.f;

#pragma unroll
    for (int n = 0; n < 4; ++n) {
#pragma unroll
        for (int rt = 0; rt < 4; ++rt) {
#pragma unroll
            for (int j = 0; j < 4; ++j) {
                float v = fmaxf(acc[rt][n][j] + bhv[n], 0.f);
#pragma unroll
                for (int off = 1; off < 16; off <<= 1) {
                    const float u = __shfl_up(v, (unsigned)off, 16);
                    if ((lane & 15) >= off) v += u;
                }
                v += carry[rt][j];
                carry[rt][j] = __shfl(v, 15, 16);
                acc[rt][n][j] = v;
            }
        }
    }

    // per-row 64-col chunk totals -> LDS for cross-wave carry
    if (tcol == 0) {
#pragma unroll
        for (int rt = 0; rt < 4; ++rt)
#pragma unroll
            for (int j = 0; j < 4; ++j) {
                const int r = rt * 16 + kq * 4 + j;
                totLds[r][wid] = carry[rt][j];
            }
    }
    __syncthreads();

#pragma unroll
    for (int rt = 0; rt < 4; ++rt) {
#pragma unroll
        for (int j = 0; j < 4; ++j) {
            const int r = rt * 16 + kq * 4 + j;
            float rc = baseLds[r];
#pragma unroll
            for (int w = 0; w < 7; ++w)
                if (w < wid) rc += totLds[r][w];
            float* orow = out + (size_t)(brow + r) * TDIM + wid * 64 + tcol;
#pragma unroll
            for (int n = 0; n < 4; ++n)
                orow[n * 16] = acc[rt][n][j] + rc;
        }
    }
}

extern "C" void kernel_launch(void* const* d_in, const int* in_sizes, int n_in,
                              void* d_out, int out_size, void* d_ws, size_t ws_size,
                              hipStream_t stream) {
    const float* x  = (const float*)d_in[0];
    const float* Wh = (const float*)d_in[1];
    const float* bh = (const float*)d_in[2];
    const float* Wb = (const float*)d_in[3];
    const float* bb = (const float*)d_in[4];
    float* out = (float*)d_out;
    __bf16* Whb = (__bf16*)d_ws;              // 1 MB scratch

    cvt_wh_kernel<<<512, 256, 0, stream>>>(Wh, Whb);
    survival_kernel<<<256, 512, 0, stream>>>(x, Whb, bh, Wb, bb, out);
}

// Round 8
// 156.540 us; speedup vs baseline: 1.0008x; 1.0008x over previous
//
#include <hip/hip_runtime.h>
#include <hip/hip_bf16.h>

// out[b,t] = cumsum_t( relu(x @ Wh^T + bh) ) + (x @ Wb + bb)
// B=16384, D=1024, T=512. fp32 in/out; GEMM in bf16 MFMA (fp32 accum).
// R6 (resubmit; R7 bench was an infra timeout): 16 waves (R3's proven lever)
//     x 3-deep counted-vmcnt pipeline (R4's, unconfounded). BK=32, triple-
//     buffered LDS (108KB). Per-wave vm ledger: steady vmcnt(8) leaves tiles
//     t+1,t+2 (xs+DMA) in flight; writeA's implicit xs-wait is vmcnt(6) ->
//     never over-drains the prefetch.

typedef __bf16 bf16x8 __attribute__((ext_vector_type(8)));
typedef __bf16 bf16x4 __attribute__((ext_vector_type(4)));
typedef float f32x4 __attribute__((ext_vector_type(4)));

typedef const __attribute__((address_space(1))) void* gas_cptr;
typedef __attribute__((address_space(3))) void* las_ptr;

#define BM 64
#define BK 32          // elements; 64 B per LDS row
#define NKIT 32        // 1024/32
#define TDIM 512
#define DDIM 1024
#define ABUF (BM * 64)     // 4 KB
#define BBUF (TDIM * 64)   // 32 KB

#define WAITV8()  asm volatile("s_waitcnt vmcnt(8) lgkmcnt(0)" ::: "memory")
#define WAITV4()  asm volatile("s_waitcnt vmcnt(4) lgkmcnt(0)" ::: "memory")
#define WAITV0()  asm volatile("s_waitcnt vmcnt(0) lgkmcnt(0)" ::: "memory")
#define WAIT_LGKM() asm volatile("s_waitcnt lgkmcnt(0)" ::: "memory")
#define SBAR()    __builtin_amdgcn_s_barrier()

// ---- kernel 1: Wh fp32 -> bf16 ----
__global__ __launch_bounds__(256) void cvt_wh_kernel(const float* __restrict__ src,
                                                     __bf16* __restrict__ dst) {
    const int i = (blockIdx.x * 256 + threadIdx.x) * 4;
    const float4 v = *reinterpret_cast<const float4*>(src + i);
    bf16x4 o;
    o[0] = (__bf16)v.x; o[1] = (__bf16)v.y; o[2] = (__bf16)v.z; o[3] = (__bf16)v.w;
    *reinterpret_cast<bf16x4*>(dst + i) = o;
}

// 64-B rows have 4 16-B slots: XOR slot with (row&3) -> 4-way conflict max
__device__ __forceinline__ int swz(int row) { return (row & 3) << 4; }

__device__ __forceinline__ unsigned int pack_bf2(float a, float b) {
    unsigned short lo = __builtin_bit_cast(unsigned short, (__bf16)a);
    unsigned short hi = __builtin_bit_cast(unsigned short, (__bf16)b);
    return ((unsigned int)hi << 16) | (unsigned int)lo;
}

// ---- kernel 2: fused GEMM + bias + relu + row-cumsum + base ----
__global__ __launch_bounds__(1024, 4) void survival_kernel(
    const float* __restrict__ x,      // [16384][1024] fp32
    const __bf16* __restrict__ Whb,   // [512][1024] bf16
    const float* __restrict__ bh,     // [512]
    const float* __restrict__ Wb,     // [1024]
    const float* __restrict__ bbp,    // [1]
    float* __restrict__ out)          // [16384][512] fp32
{
    __shared__ __align__(16) char Alds[3][ABUF];   // 12 KB
    __shared__ __align__(16) char Blds[3][BBUF];   // 96 KB
    __shared__ float baseLds[BM];
    __shared__ float totLds[BM][8];

    const int tid  = threadIdx.x;
    const int lane = tid & 63;
    const int wid  = tid >> 6;     // 0..15
    const int wm   = wid >> 3;     // 0..1  (row half: 32 rows)
    const int wn   = wid & 7;      // 0..7  (col eighth: 64 cols)
    const int tcol = lane & 15;
    const int kq   = lane >> 4;
    const int brow = blockIdx.x * BM;
    const float bb0 = bbp[0];

    // --- A staging: row = tid>>4 (0..63), pair = tid&15 (2 fp32 = 4B bf16) ---
    const int ar = tid >> 4;
    const int ap = tid & 15;
    const float* xrow = x + (size_t)(brow + ar) * DDIM + ap * 2;
    const float* wbp  = Wb + ap * 2;
    const int a_byte = ar * 64 + ((ap * 4) ^ swz(ar));

    // --- B staging: per wave 2 DMAs of 1 KB (16 rows each) ---
    const int b_row0 = wid * 32 + (lane >> 2);
    const int b_s    = lane & 3;

    float bpart = 0.f;
    f32x4 acc[2][4];
#pragma unroll
    for (int rt = 0; rt < 2; ++rt)
#pragma unroll
        for (int n = 0; n < 4; ++n)
            acc[rt][n] = (f32x4){0.f, 0.f, 0.f, 0.f};

    float2 xr0, wr0, xr1, wr1;   // xs slots (parity t&1; static under unroll)

    // issue order per tile: xs FIRST, then B-DMA (writeA's xs-wait then
    // leaves all B-DMA in flight).
    auto issueT = [&](int buf, int it, int slot) {
        const int k0 = it * BK;
        if (slot == 0) { xr0 = *reinterpret_cast<const float2*>(xrow + k0);
                         wr0 = *reinterpret_cast<const float2*>(wbp + k0); }
        else           { xr1 = *reinterpret_cast<const float2*>(xrow + k0);
                         wr1 = *reinterpret_cast<const float2*>(wbp + k0); }
#pragma unroll
        for (int c = 0; c < 2; ++c) {
            const int row = b_row0 + c * 16;
            const int cb  = (b_s * 16) ^ swz(row);   // inverse-swizzled source
            const __bf16* g = Whb + (size_t)row * DDIM + k0 + (cb >> 1);
            char* l = &Blds[buf][0] + (wid * 32 + c * 16) * 64;  // linear dest
            __builtin_amdgcn_global_load_lds((gas_cptr)(const void*)g,
                                             (las_ptr)(void*)l, 16, 0, 0);
        }
    };

    auto writeA = [&](int buf, int slot) {
        const float2 xv = slot ? xr1 : xr0;
        const float2 wv = slot ? wr1 : wr0;
        bpart += xv.x * wv.x + xv.y * wv.y;
        *reinterpret_cast<unsigned int*>(&Alds[buf][0] + a_byte) = pack_bf2(xv.x, xv.y);
    };

    auto compute = [&](int buf) {
        const char* Ab = &Alds[buf][0];
        const char* Bb = &Blds[buf][0];
        const int sl = kq * 16;
        bf16x8 af[2];
#pragma unroll
        for (int rt = 0; rt < 2; ++rt) {
            const int row = wm * 32 + rt * 16 + tcol;
            af[rt] = *reinterpret_cast<const bf16x8*>(Ab + row * 64 + (sl ^ swz(row)));
        }
        __builtin_amdgcn_s_setprio(1);
#pragma unroll
        for (int n = 0; n < 4; ++n) {
            const int trow = wn * 64 + n * 16 + tcol;
            const bf16x8 bfr = *reinterpret_cast<const bf16x8*>(
                Bb + trow * 64 + (sl ^ swz(trow)));
            acc[0][n] = __builtin_amdgcn_mfma_f32_16x16x32_bf16(af[0], bfr, acc[0][n], 0, 0, 0);
            acc[1][n] = __builtin_amdgcn_mfma_f32_16x16x32_bf16(af[1], bfr, acc[1][n], 0, 0, 0);
        }
        __builtin_amdgcn_s_setprio(0);
    };

    // --- prologue: tiles 0,1 in flight; A[0] in LDS ---
    issueT(0, 0, 0);
    issueT(1, 1, 1);
    writeA(0, 0);        // waits xs0 only (vmcnt<=6); B0,xs1,B1 stay in flight

    // --- 3-deep pipelined K loop ---
    // ledger at top of iter t (after issueT(t+2)):
    //   [B(t)2, xs(t+1)2, B(t+1)2, xs(t+2)2, B(t+2)2] = 10 -> vmcnt(8) drains B(t)
#pragma unroll
    for (int t = 0; t < NKIT; ++t) {
        if (t + 2 < NKIT) issueT((t + 2) % 3, t + 2, t & 1);
        if (t + 2 < NKIT)      WAITV8();
        else if (t + 1 < NKIT) WAITV4();
        else                   WAITV0();
        SBAR();                               // tile t in LDS for all waves
        compute(t % 3);
        if (t + 1 < NKIT) writeA((t + 1) % 3, (t + 1) & 1);
        WAIT_LGKM();                          // frag reads + A-write drained
        SBAR();                               // buf[t%3] reusable by B(t+3)
    }

    // --- base = x@Wb + bb : reduce 16 pair-partials per row ---
    bpart += __shfl_xor(bpart, 1, 16);
    bpart += __shfl_xor(bpart, 2, 16);
    bpart += __shfl_xor(bpart, 4, 16);
    bpart += __shfl_xor(bpart, 8, 16);
    if (ap == 0) baseLds[ar] = bpart + bb0;

    // --- epilogue: bias + relu + in-register inclusive scan over T ---
    // C layout (m89): col = lane&15, row = (lane>>4)*4 + j within 16x16 tile
    float bhv[4];
#pragma unroll
    for (int n = 0; n < 4; ++n)
        bhv[n] = bh[wn * 64 + n * 16 + tcol];

    float carry[2][4] = {{0.f,0.f,0.f,0.f},{0.f,0.f,0.f,0.f}};
#pragma unroll
    for (int n = 0; n < 4; ++n) {
#pragma unroll
        for (int rt = 0; rt < 2; ++rt) {
#pragma unroll
            for (int j = 0; j < 4; ++j) {
                float v = fmaxf(acc[rt][n][j] + bhv[n], 0.f);
#pragma unroll
                for (int off = 1; off < 16; off <<= 1) {
                    const float u = __shfl_up(v, (unsigned)off, 16);
                    if (tcol >= off) v += u;
                }
                v += carry[rt][j];
                carry[rt][j] = __shfl(v, 15, 16);
                acc[rt][n][j] = v;
            }
        }
    }

    // per-row 64-col chunk totals -> LDS for cross-wave carry
    if (tcol == 0) {
#pragma unroll
        for (int rt = 0; rt < 2; ++rt)
#pragma unroll
            for (int j = 0; j < 4; ++j) {
                const int r = wm * 32 + rt * 16 + kq * 4 + j;
                totLds[r][wn] = carry[rt][j];
            }
    }
    __syncthreads();

#pragma unroll
    for (int rt = 0; rt < 2; ++rt) {
#pragma unroll
        for (int j = 0; j < 4; ++j) {
            const int r = wm * 32 + rt * 16 + kq * 4 + j;
            float rc = baseLds[r];
#pragma unroll
            for (int w = 0; w < 7; ++w)
                if (w < wn) rc += totLds[r][w];
            float* orow = out + (size_t)(brow + r) * TDIM + wn * 64 + tcol;
#pragma unroll
            for (int n = 0; n < 4; ++n)
                orow[n * 16] = acc[rt][n][j] + rc;
        }
    }
}

extern "C" void kernel_launch(void* const* d_in, const int* in_sizes, int n_in,
                              void* d_out, int out_size, void* d_ws, size_t ws_size,
                              hipStream_t stream) {
    const float* x  = (const float*)d_in[0];
    const float* Wh = (const float*)d_in[1];
    const float* bh = (const float*)d_in[2];
    const float* Wb = (const float*)d_in[3];
    const float* bb = (const float*)d_in[4];
    float* out = (float*)d_out;
    __bf16* Whb = (__bf16*)d_ws;              // 1 MB scratch

    cvt_wh_kernel<<<512, 256, 0, stream>>>(Wh, Whb);
    survival_kernel<<<256, 1024, 0, stream>>>(x, Whb, bh, Wb, bb, out);
}

// Round 10
// 133.809 us; speedup vs baseline: 1.1708x; 1.1699x over previous
//
#include <hip/hip_runtime.h>
#include <hip/hip_bf16.h>

// out[b,t] = cumsum_t( relu(x @ Wh^T + bh) ) + (x @ Wb + bb)
// B=16384, D=1024, T=512. fp32 in/out; GEMM in bf16 MFMA (fp32 accum).
// R9: R8 structure (barrier-free K-loop; Wh pre-transposed to MFMA-fragment
//     order -> B is one coalesced 1KB L2 load per step, no LDS/no barrier;
//     A staged ONCE in LDS in 4 chunks) with the B-stride units bug fixed:
//     fragment blocks are 512 ELEMENTS (1024 bytes); R8 indexed *1024 elems
//     -> OOB reads for wid>=4 -> absmax 95. Three offsets corrected.

typedef __bf16 bf16x8 __attribute__((ext_vector_type(8)));
typedef float f32x4 __attribute__((ext_vector_type(4)));

#define TDIM 512
#define DDIM 1024
#define BM 64
#define NCH 4            // fill chunks (K=256 each)
#define KS_PER_CH 8      // k-steps (K=32) per chunk
#define BLKE 512         // elements per fragment block (64 lanes x 8)

// ---- kernel 1: Wh fp32 -> bf16 in MFMA-fragment order ----
// dst block (tt,ks) is 64 lanes x 16B: lane l holds Wh[tt*16+(l&15)][ks*32+(l>>4)*8 +0..7]
__global__ __launch_bounds__(256) void prep_wh(const float* __restrict__ src,
                                               __bf16* __restrict__ dst) {
    const int i    = blockIdx.x * 256 + threadIdx.x;   // 0..65535
    const int lane = i & 63;
    const int blk  = i >> 6;          // tt*32 + ks
    const int tt   = blk >> 5;
    const int ks   = blk & 31;
    const int row  = tt * 16 + (lane & 15);
    const int k    = ks * 32 + (lane >> 4) * 8;
    const float4 a = *reinterpret_cast<const float4*>(src + (size_t)row * DDIM + k);
    const float4 b = *reinterpret_cast<const float4*>(src + (size_t)row * DDIM + k + 4);
    bf16x8 o;
    o[0] = (__bf16)a.x; o[1] = (__bf16)a.y; o[2] = (__bf16)a.z; o[3] = (__bf16)a.w;
    o[4] = (__bf16)b.x; o[5] = (__bf16)b.y; o[6] = (__bf16)b.z; o[7] = (__bf16)b.w;
    *reinterpret_cast<bf16x8*>(dst + (size_t)i * 8) = o;
}

// ---- kernel 2: fused GEMM + bias + relu + row-cumsum + base ----
__global__ __launch_bounds__(1024, 4) void survival_kernel(
    const float* __restrict__ x,      // [16384][1024] fp32
    const __bf16* __restrict__ Whb,   // [512*1024] bf16, fragment order
    const float* __restrict__ bh,     // [512]
    const float* __restrict__ Wb,     // [1024]
    const float* __restrict__ bbp,    // [1]
    float* __restrict__ out)          // [16384][512] fp32
{
    // A: [64 rows][128 slots of 16B], slot' = slot ^ (row&7)  (2-way reads = free)
    __shared__ __align__(16) char Abf[BM * 2048];   // 128 KB
    __shared__ float baseLds[BM];
    __shared__ float totLds[BM][16];

    const int tid  = threadIdx.x;
    const int lane = tid & 63;
    const int wid  = tid >> 6;      // 0..15: wave owns T-cols [wid*32, wid*32+32)
    const int am   = lane & 15;     // M-col of A frag / T-col of C
    const int kq   = lane >> 4;     // k-quarter
    const int brow = blockIdx.x * BM;
    const float bb0 = bbp[0];

    // --- fill mapping: row ar = tid>>4, slot pair {c*32+ap, c*32+ap+16} ---
    const int ar = tid >> 4;
    const int ap = tid & 15;
    const float* xrow = x + (size_t)(brow + ar) * DDIM;

    float bpart = 0.f;
    f32x4 acc[4][2];
#pragma unroll
    for (int rt = 0; rt < 4; ++rt)
#pragma unroll
        for (int n = 0; n < 2; ++n)
            acc[rt][n] = (f32x4){0.f, 0.f, 0.f, 0.f};

    float4 xs0, xs1, xs2, xs3;   // in-flight fill regs (named: static, no scratch)

    auto issueFill = [&](int c) {
        const int k0 = c * 256 + ap * 8;
        xs0 = *reinterpret_cast<const float4*>(xrow + k0);
        xs1 = *reinterpret_cast<const float4*>(xrow + k0 + 4);
        xs2 = *reinterpret_cast<const float4*>(xrow + k0 + 128);
        xs3 = *reinterpret_cast<const float4*>(xrow + k0 + 132);
    };

    auto writeFill = [&](int c) {
        const int k0 = c * 256 + ap * 8;
        const float4 w0 = *reinterpret_cast<const float4*>(Wb + k0);
        const float4 w1 = *reinterpret_cast<const float4*>(Wb + k0 + 4);
        const float4 w2 = *reinterpret_cast<const float4*>(Wb + k0 + 128);
        const float4 w3 = *reinterpret_cast<const float4*>(Wb + k0 + 132);
        bpart += xs0.x*w0.x + xs0.y*w0.y + xs0.z*w0.z + xs0.w*w0.w
               + xs1.x*w1.x + xs1.y*w1.y + xs1.z*w1.z + xs1.w*w1.w
               + xs2.x*w2.x + xs2.y*w2.y + xs2.z*w2.z + xs2.w*w2.w
               + xs3.x*w3.x + xs3.y*w3.y + xs3.z*w3.z + xs3.w*w3.w;
        bf16x8 v0, v1;
        v0[0]=(__bf16)xs0.x; v0[1]=(__bf16)xs0.y; v0[2]=(__bf16)xs0.z; v0[3]=(__bf16)xs0.w;
        v0[4]=(__bf16)xs1.x; v0[5]=(__bf16)xs1.y; v0[6]=(__bf16)xs1.z; v0[7]=(__bf16)xs1.w;
        v1[0]=(__bf16)xs2.x; v1[1]=(__bf16)xs2.y; v1[2]=(__bf16)xs2.z; v1[3]=(__bf16)xs2.w;
        v1[4]=(__bf16)xs3.x; v1[5]=(__bf16)xs3.y; v1[6]=(__bf16)xs3.z; v1[7]=(__bf16)xs3.w;
        const int s0 = c * 32 + ap;
        const int s1 = s0 + 16;
        *reinterpret_cast<bf16x8*>(&Abf[0] + ar * 2048 + ((s0 ^ (ar & 7)) * 16)) = v0;
        *reinterpret_cast<bf16x8*>(&Abf[0] + ar * 2048 + ((s1 ^ (ar & 7)) * 16)) = v1;
    };

    // wave's B base: t-tiles 2*wid and 2*wid+1; block (tt,ks) at elems (tt*32+ks)*BLKE
    const __bf16* bbase = Whb + (size_t)(wid * 2) * 32 * BLKE + (size_t)lane * 8;

    auto computeChunk = [&](int c) {
#pragma unroll
        for (int s = 0; s < KS_PER_CH; ++s) {
            const int ks = c * KS_PER_CH + s;
            const bf16x8 b0 = *reinterpret_cast<const bf16x8*>(bbase + (size_t)ks * BLKE);
            const bf16x8 b1 = *reinterpret_cast<const bf16x8*>(bbase + (size_t)(32 + ks) * BLKE);
            bf16x8 af[4];
#pragma unroll
            for (int rt = 0; rt < 4; ++rt) {
                const int row = rt * 16 + am;
                const int slot = (ks * 4 + kq) ^ (am & 7);
                af[rt] = *reinterpret_cast<const bf16x8*>(&Abf[0] + row * 2048 + slot * 16);
            }
            __builtin_amdgcn_s_setprio(1);
#pragma unroll
            for (int rt = 0; rt < 4; ++rt) {
                acc[rt][0] = __builtin_amdgcn_mfma_f32_16x16x32_bf16(af[rt], b0, acc[rt][0], 0, 0, 0);
                acc[rt][1] = __builtin_amdgcn_mfma_f32_16x16x32_bf16(af[rt], b1, acc[rt][1], 0, 0, 0);
            }
            __builtin_amdgcn_s_setprio(0);
        }
    };

    // --- main: 5 barriers total, no barriers inside compute ---
    issueFill(0);
    writeFill(0);
    __syncthreads();
#pragma unroll
    for (int c = 0; c < NCH; ++c) {
        if (c + 1 < NCH) issueFill(c + 1);    // HBM latency hides under compute
        computeChunk(c);
        if (c + 1 < NCH) { writeFill(c + 1); __syncthreads(); }
    }

    // --- base = x@Wb + bb : reduce 16 partials per row (16-lane groups) ---
    bpart += __shfl_xor(bpart, 1, 16);
    bpart += __shfl_xor(bpart, 2, 16);
    bpart += __shfl_xor(bpart, 4, 16);
    bpart += __shfl_xor(bpart, 8, 16);
    if (ap == 0) baseLds[ar] = bpart + bb0;

    // --- epilogue: bias + relu + in-register inclusive scan over T ---
    // C layout (m89): col(T) = am, row(M) = kq*4 + j within each 16x16 tile
    float bhv[2];
#pragma unroll
    for (int n = 0; n < 2; ++n)
        bhv[n] = bh[wid * 32 + n * 16 + am];

    float carry[4][4];
#pragma unroll
    for (int rt = 0; rt < 4; ++rt)
#pragma unroll
        for (int j = 0; j < 4; ++j) carry[rt][j] = 0.f;

#pragma unroll
    for (int n = 0; n < 2; ++n) {
#pragma unroll
        for (int rt = 0; rt < 4; ++rt) {
#pragma unroll
            for (int j = 0; j < 4; ++j) {
                float v = fmaxf(acc[rt][n][j] + bhv[n], 0.f);
#pragma unroll
                for (int off = 1; off < 16; off <<= 1) {
                    const float u = __shfl_up(v, (unsigned)off, 16);
                    if (am >= off) v += u;
                }
                v += carry[rt][j];
                carry[rt][j] = __shfl(v, 15, 16);
                acc[rt][n][j] = v;
            }
        }
    }

    // per-row 32-col wave totals -> LDS for cross-wave carry
    if (am == 0) {
#pragma unroll
        for (int rt = 0; rt < 4; ++rt)
#pragma unroll
            for (int j = 0; j < 4; ++j)
                totLds[rt * 16 + kq * 4 + j][wid] = carry[rt][j];
    }
    __syncthreads();

#pragma unroll
    for (int rt = 0; rt < 4; ++rt) {
#pragma unroll
        for (int j = 0; j < 4; ++j) {
            const int r = rt * 16 + kq * 4 + j;
            float rc = baseLds[r];
#pragma unroll
            for (int w = 0; w < 15; ++w)
                if (w < wid) rc += totLds[r][w];
            float* orow = out + (size_t)(brow + r) * TDIM + wid * 32 + am;
            orow[0]  = acc[rt][0][j] + rc;
            orow[16] = acc[rt][1][j] + rc;
        }
    }
}

extern "C" void kernel_launch(void* const* d_in, const int* in_sizes, int n_in,
                              void* d_out, int out_size, void* d_ws, size_t ws_size,
                              hipStream_t stream) {
    const float* x  = (const float*)d_in[0];
    const float* Wh = (const float*)d_in[1];
    const float* bh = (const float*)d_in[2];
    const float* Wb = (const float*)d_in[3];
    const float* bb = (const float*)d_in[4];
    float* out = (float*)d_out;
    __bf16* Whb = (__bf16*)d_ws;              // 1 MB scratch, fragment-ordered

    prep_wh<<<256, 256, 0, stream>>>(Wh, Whb);
    survival_kernel<<<256, 1024, 0, stream>>>(x, Whb, bh, Wb, bb, out);
}